// Round 7
// baseline (439.012 us; speedup 1.0000x reference)
//
#include <hip/hip_runtime.h>
#include <stdint.h>

#define NTAGS 256
#define BATCH 64
#define SEQ   512
#define MB    16          // batches per workgroup-chain (the mfma N dimension)
#define NTHREADS 512      // 8 waves: waves 0-3 = fwd chain, waves 4-7 = bwd chain

typedef __attribute__((ext_vector_type(8))) short short8;   // 8 bf16 (4 VGPRs)
typedef __attribute__((ext_vector_type(4))) float f32x4;

__device__ __forceinline__ unsigned int f32_to_bf16_bits(float f) {
  unsigned int u = __float_as_uint(f);
  return (u + 0x7FFFu + ((u >> 16) & 1u)) >> 16;
}
__device__ __forceinline__ float wave_sum(float v) {
#pragma unroll
  for (int o = 32; o; o >>= 1) v += __shfl_xor(v, o);
  return v;
}
__device__ __forceinline__ unsigned int pk_bf16(float lo, float hi) {
  unsigned int r;
  asm("v_cvt_pk_bf16_f32 %0, %1, %2" : "=v"(r) : "v"(lo), "v"(hi));
  return r;
}

#define LOG2E 1.4426950408889634f

// lgkm-only barrier: LDS writes ordered; global prefetch loads stay in flight.
// ALWAYS in straight-line code (all 8 waves, same program point).
#define BAR_LGKM() \
    asm volatile("s_waitcnt lgkmcnt(0)" ::: "memory"); \
    __builtin_amdgcn_s_barrier(); \
    asm volatile("" ::: "memory");

// One mfma sweep: D[tag',batch] += E' * alpha, 8 K-chunks, 4 M-tiles (acc0..3).
#define MFMA_ALL(RB) \
    f32x4 acc0 = {0.f,0.f,0.f,0.f}, acc1 = {0.f,0.f,0.f,0.f}, \
          acc2 = {0.f,0.f,0.f,0.f}, acc3 = {0.f,0.f,0.f,0.f}; \
    _Pragma("unroll") \
    for (int c = 0; c < 8; ++c) { \
      const short8 bf = *(const short8*)&aldsC[RB][bidxs[c]]; \
      acc0 = __builtin_amdgcn_mfma_f32_16x16x32_bf16(aF[0][c], bf, acc0, 0, 0, 0); \
      acc1 = __builtin_amdgcn_mfma_f32_16x16x32_bf16(aF[1][c], bf, acc1, 0, 0, 0); \
      acc2 = __builtin_amdgcn_mfma_f32_16x16x32_bf16(aF[2][c], bf, acc2, 0, 0, 0); \
      acc3 = __builtin_amdgcn_mfma_f32_16x16x32_bf16(aF[3][c], bf, acc3, 0, 0, 0); \
    }

// Unified epilogue tile. C/D layout (m89): lane col=p, rows tag'=64cw+16I+4q+r.
// fastm (all-ones mask, the bench case): n = acc*P*sc for both chains.
// slow fwd: masked keeps old (*sc).  slow bwd: masked = old * P_t/P_{t+1} (*sc).
// The slow paths are wave-divergent but contain NO barrier.
#define EPI_TILE(I, ACCI, PB, WB, ME) { \
      const uint2 pw = PB[I]; \
      const float p0_ = __uint_as_float(pw.x << 16); \
      const float p1_ = __uint_as_float(pw.x & 0xFFFF0000u); \
      const float p2_ = __uint_as_float(pw.y << 16); \
      const float p3_ = __uint_as_float(pw.y & 0xFFFF0000u); \
      float n0, n1, n2, n3; \
      if (fastm) { \
        n0 = ACCI[0] * p0_ * sc; n1 = ACCI[1] * p1_ * sc; \
        n2 = ACCI[2] * p2_ * sc; n3 = ACCI[3] * p3_ * sc; \
      } else if (!chain) { \
        n0 = (MM ? ACCI[0] * p0_ : sOld[I][0]) * sc; \
        n1 = (MM ? ACCI[1] * p1_ : sOld[I][1]) * sc; \
        n2 = (MM ? ACCI[2] * p2_ : sOld[I][2]) * sc; \
        n3 = (MM ? ACCI[3] * p3_ : sOld[I][3]) * sc; \
      } else { \
        const float q0_ = __uint_as_float(gp[I].x << 16); \
        const float q1_ = __uint_as_float(gp[I].x & 0xFFFF0000u); \
        const float q2_ = __uint_as_float(gp[I].y << 16); \
        const float q3_ = __uint_as_float(gp[I].y & 0xFFFF0000u); \
        n0 = (MM ? ACCI[0] * p0_ : sOld[I][0] * (p0_ / q0_)) * sc; \
        n1 = (MM ? ACCI[1] * p1_ : sOld[I][1] * (p1_ / q1_)) * sc; \
        n2 = (MM ? ACCI[2] * p2_ : sOld[I][2] * (p2_ / q2_)) * sc; \
        n3 = (MM ? ACCI[3] * p3_ : sOld[I][3] * (p3_ / q3_)) * sc; \
      } \
      gp[I] = pw; \
      sOld[I][0] = n0; sOld[I][1] = n1; sOld[I][2] = n2; sOld[I][3] = n3; \
      if (ME) mxl = fmaxf(mxl, fmaxf(fmaxf(n0, n1), fmaxf(n2, n3))); \
      uint2 wv; wv.x = pk_bf16(n0, n1); wv.y = pk_bf16(n2, n3); \
      *(uint2*)&aldsC[WB][widx[I]] = wv; }

// Unified step s (fwd t=s, bwd t=511-s; APPLY at s%4==0, MEAS at s%4==3 for
// BOTH chains). Top-of-step prefetch into 4-buffer rotation; ONE barrier,
// straight-line, shared by all 8 waves.
#define STEP(S, RB, WB, PC, PL, MC, ML, APPLY, MEAS) { \
    { int tpP_ = chain ? 509 - (S) : (S) + 2; \
      int tpM_ = chain ? 510 - (S) : (S) + 2; \
      tpP_ = tpP_ < 0 ? 0 : (tpP_ > SEQ - 1 ? SEQ - 1 : tpP_); \
      tpM_ = tpM_ < 0 ? 0 : (tpM_ > SEQ - 1 ? SEQ - 1 : tpM_); \
      _Pragma("unroll") \
      for (int i2 = 0; i2 < 4; ++i2) PL[i2] = *(const uint2*)(Pp + (size_t)tpP_ * NTAGS + 16 * i2); \
      ML = mkp[tpM_]; } \
    MFMA_ALL(RB) \
    float sc = 1.0f; \
    if (APPLY) { \
      const f32x4 mx4 = *(const f32x4*)&maxwC[p][0]; \
      const float mx = fmaxf(fmaxf(mx4[0], mx4[1]), fmaxf(mx4[2], mx4[3])); \
      const int e = (int)((__float_as_uint(mx) >> 23) & 0xFF) - 127; \
      esum += e; \
      sc = __uint_as_float((unsigned int)(127 - e) << 23); \
    } \
    const int MM = MC; \
    const bool fastm = (bool)__all(MM != 0); \
    float mxl = -3.0e38f; \
    EPI_TILE(0, acc0, PC, WB, MEAS) EPI_TILE(1, acc1, PC, WB, MEAS) \
    EPI_TILE(2, acc2, PC, WB, MEAS) EPI_TILE(3, acc3, PC, WB, MEAS) \
    if (MEAS) { \
      float v = mxl; v = fmaxf(v, __shfl_xor(v, 16)); v = fmaxf(v, __shfl_xor(v, 32)); \
      if (q == 0) maxwC[p][cw] = v; \
    } \
    BAR_LGKM() }

// Prep: P[b][t][k] = e^{logits} as bf16. Fully parallel, memory-bound (~10us).
__global__ __launch_bounds__(256)
void crf_prep(const float* __restrict__ lg, unsigned int* __restrict__ P)
{
  const size_t g = (size_t)blockIdx.x * 256 + threadIdx.x;   // 8 floats / thread
  const float4 a = ((const float4*)lg)[2 * g];
  const float4 b = ((const float4*)lg)[2 * g + 1];
  uint4 o;
  o.x = pk_bf16(exp2f(a.x * LOG2E), exp2f(a.y * LOG2E));
  o.y = pk_bf16(exp2f(a.z * LOG2E), exp2f(a.w * LOG2E));
  o.z = pk_bf16(exp2f(b.x * LOG2E), exp2f(b.y * LOG2E));
  o.w = pk_bf16(exp2f(b.z * LOG2E), exp2f(b.w * LOG2E));
  ((uint4*)P)[g] = o;
}

// Pass 1: 4 blocks x 512 threads. Waves 0-3: forward chain alpha_0 -> alpha_255.
// Waves 4-7: backward chain c_511 -> c_256 -> b_255. Same 16 batches per block.
// All barriers are straight-line and shared; chain-ness is pure data.
__global__ __launch_bounds__(NTHREADS, 1)
void crf_halves(const unsigned short* __restrict__ P,
                const int*   __restrict__ mask,
                const float* __restrict__ trans,
                float* __restrict__ wsA, float* __restrict__ wsB,
                int* __restrict__ wseF, int* __restrict__ wseB)
{
  const int bid   = blockIdx.x;
  const int b0    = bid * MB;
  const int tid   = threadIdx.x;
  const int wid   = tid >> 6;        // 0..7
  const int chain = wid >> 2;        // 0 = fwd, 1 = bwd (wave-uniform)
  const int cw    = wid & 3;         // wave-in-chain -> tag' range [64*cw, +64)
  const int lane  = tid & 63;
  const int p     = lane & 15;       // batch column (mfma N / C-col)
  const int q     = lane >> 4;       // k-group (mfma A/B row-group)

  __shared__ __align__(16) short alds[2][2][NTAGS * MB];  // [chain][dbuf], XOR-swz
  __shared__ __align__(16) float maxw[2][16][4];          // [chain][batch][wave]

  short (*aldsC)[NTAGS * MB] = alds[chain];
  float (*maxwC)[4]          = maxw[chain];

  const unsigned short* Pp = P + (size_t)(b0 + p) * SEQ * NTAGS + 64 * cw + 4 * q;
  const int* mkp = mask + (b0 + p) * SEQ;

  int bidxs[8], widx[4];
#pragma unroll
  for (int c = 0; c < 8; ++c) bidxs[c] = (p * NTAGS + 32 * c + 8 * q) ^ ((p & 7) << 3);
#pragma unroll
  for (int i = 0; i < 4; ++i) widx[i] = (p * NTAGS + 64 * cw + 16 * i + 4 * q) ^ ((p & 7) << 3);

  // ---- E fragments in registers (constant across steps; 128 VGPRs) ----
  // fwd: A[m=tag',k=tag] = exp(trans[tag, tag']);  bwd: exp(trans[tag', tag]).
  short8 aF[4][8];
#pragma unroll
  for (int i = 0; i < 4; ++i) {
    const int m = 64 * cw + 16 * i + p;   // A-row for this lane
#pragma unroll
    for (int c = 0; c < 8; ++c) {
      short8 w;
#pragma unroll
      for (int j = 0; j < 8; ++j) {
        const int tag = 32 * c + 8 * q + j;
        const float tv = chain ? trans[m * NTAGS + tag] : trans[tag * NTAGS + m];
        w[j] = (short)f32_to_bf16_bits(exp2f(tv * LOG2E));
      }
      aF[i][c] = w;
    }
  }

  f32x4 sOld[4];
  uint2 p0[4], p1[4], p2[4], p3[4], gp[4];   // P rotation (4 buffers) + bwd prev-P
  int m0 = 1, m1 = 1, m2 = 1, m3 = 1;
  int esum = 0;

  // ---- init (divergent DATA only; no barriers inside) ----
  {
    const int t0  = chain ? (SEQ - 1) : 0;   // state init time
    const int t1P = chain ? 510 : 1;         // P for step s=1
    const int t1M = chain ? 511 : 1;         // gate for step s=1
    const int t2P = chain ? 509 : 2;         // P for step s=2
    const int t2M = chain ? 510 : 2;         // gate for step s=2
#pragma unroll
    for (int i = 0; i < 4; ++i) {
      const uint2 pw = *(const uint2*)(Pp + (size_t)t0 * NTAGS + 16 * i);
      f32x4 a;
      a[0] = __uint_as_float(pw.x << 16); a[1] = __uint_as_float(pw.x & 0xFFFF0000u);
      a[2] = __uint_as_float(pw.y << 16); a[3] = __uint_as_float(pw.y & 0xFFFF0000u);
      sOld[i] = a; gp[i] = pw;
      *(uint2*)&aldsC[0][widx[i]] = pw;                  // already bf16-packed
    }
#pragma unroll
    for (int i = 0; i < 4; ++i) {
      p1[i] = *(const uint2*)(Pp + (size_t)t1P * NTAGS + 16 * i);
      p2[i] = *(const uint2*)(Pp + (size_t)t2P * NTAGS + 16 * i);
    }
    m1 = mkp[t1M]; m2 = mkp[t2M];
  }
  __syncthreads();                                       // barrier #1 (shared)

  // ---- main: 254 unified steps, one shared barrier each (#2..#255) ----
  STEP(1, 0, 1, p1, p3, m1, m3, 0, 0)
  STEP(2, 1, 0, p2, p0, m2, m0, 0, 0)
  STEP(3, 0, 1, p3, p1, m3, m1, 0, 1)
#pragma unroll 1
  for (int s0 = 4; s0 <= 248; s0 += 4) {
    STEP(s0 + 0, 1, 0, p0, p2, m0, m2, 1, 0)
    STEP(s0 + 1, 0, 1, p1, p3, m1, m3, 0, 0)
    STEP(s0 + 2, 1, 0, p2, p0, m2, m0, 0, 0)
    STEP(s0 + 3, 0, 1, p3, p1, m3, m1, 0, 1)
  }
  STEP(252, 1, 0, p0, p2, m0, m2, 1, 0)
  STEP(253, 0, 1, p1, p3, m1, m3, 0, 0)
  STEP(254, 1, 0, p2, p0, m2, m0, 0, 0)

  // ---- tail s=255 (RB=0, p3/m3): fwd final-special, bwd normal step ----
  {
    MFMA_ALL(0)
    if (!chain) {
      // fwd t=255: no renorm; write f32 alpha_255 to workspace (global only)
      const int MM = m3;    // mk[255] (loaded at s=253)
      float* wp = wsA + (size_t)(b0 + p) * NTAGS + 64 * cw + 4 * q;
#pragma unroll
      for (int i = 0; i < 4; ++i) {
        const uint2 pw = p3[i];   // P[255] (loaded at s=253)
        f32x4 pv;
        pv[0] = __uint_as_float(pw.x << 16); pv[1] = __uint_as_float(pw.x & 0xFFFF0000u);
        pv[2] = __uint_as_float(pw.y << 16); pv[3] = __uint_as_float(pw.y & 0xFFFF0000u);
        f32x4 o;
        const f32x4 ac = (i == 0) ? acc0 : (i == 1) ? acc1 : (i == 2) ? acc2 : acc3;
#pragma unroll
        for (int r = 0; r < 4; ++r)
          o[r] = MM ? ac[r] * pv[r] : sOld[i][r];
        *(f32x4*)(wp + 16 * i) = o;
      }
      if (wid == 0 && lane < 16) wseF[b0 + lane] = esum;
    } else {
      // bwd t=256: normal epilogue (no APPLY/MEAS), writes c_256 into buf 1
      const float sc = 1.0f;
      const int MM = m3;    // mk[257] (loaded at s=253)
      const bool fastm = (bool)__all(MM != 0);
      float mxl = -3.0e38f;
      EPI_TILE(0, acc0, p3, 1, 0) EPI_TILE(1, acc1, p3, 1, 0)
      EPI_TILE(2, acc2, p3, 1, 0) EPI_TILE(3, acc3, p3, 1, 0)
      (void)mxl;
    }
  }
  BAR_LGKM()                                             // barrier #256 (shared)

  if (chain) {
    // bare matvec b_255 = E * c_256 (no e^g), store f32
    MFMA_ALL(1)
    float* wp = wsB + (size_t)(b0 + p) * NTAGS + 64 * cw + 4 * q;
    *(f32x4*)(wp + 0)  = acc0;
    *(f32x4*)(wp + 16) = acc1;
    *(f32x4*)(wp + 32) = acc2;
    *(f32x4*)(wp + 48) = acc3;
    if (cw == 0 && lane < 16) wseB[b0 + lane] = esum;
  }
}

// Pass 2: numerator + den = log(sum a_255 . b_255) + (Ef+Eb)*ln2
__global__ __launch_bounds__(256)
void crf_combine(const float* __restrict__ logits,
                 const int*   __restrict__ tags,
                 const int*   __restrict__ mask,
                 const float* __restrict__ trans,
                 const float* __restrict__ wsA,
                 const float* __restrict__ wsB,
                 const int*   __restrict__ wseF,
                 const int*   __restrict__ wseB,
                 float* __restrict__ out)
{
  const int b    = blockIdx.x;
  const int tid  = threadIdx.x;
  const int lane = tid & 63;
  const int wid  = tid >> 6;   // 0..3

  __shared__ float rn[4], rm[4], rp[4];

  const float LN2 = 0.6931471805599453f;
  const float* lg = logits + (size_t)b * SEQ * NTAGS;
  const int*   tg = tags + b * SEQ;
  const int*   mk = mask + b * SEQ;

  float numer = 0.f, msum = 0.f;
  for (int t = tid; t < SEQ; t += 256) {
    int   tag_t = tg[t];
    float m_t   = (float)mk[t];
    msum += m_t;
    if (t < SEQ - 1) {
      numer += lg[t * NTAGS + tag_t] * m_t;
      numer += trans[tag_t * NTAGS + tg[t + 1]] * (float)mk[t + 1];
    }
  }
  numer = wave_sum(numer);
  msum  = wave_sum(msum);
  if (lane == 0) { rn[wid] = numer; rm[wid] = msum; }

  float pprod = wsA[b * NTAGS + tid] * wsB[b * NTAGS + tid];
  pprod = wave_sum(pprod);
  if (lane == 0) rp[wid] = pprod;
  __syncthreads();

  if (tid == 0) {
    const float numer_tot = (rn[0] + rn[1]) + (rn[2] + rn[3]);
    const float msum_tot  = (rm[0] + rm[1]) + (rm[2] + rm[3]);
    const float psum      = (rp[0] + rp[1]) + (rp[2] + rp[3]);
    const float log_den   = logf(psum) + (float)(wseF[b] + wseB[b]) * LN2;
    int last_idx = (int)msum_tot - 1;
    if (last_idx < 0) last_idx = 0;
    const int last_tag = tg[last_idx];
    const float score = numer_tot + lg[(SEQ - 1) * NTAGS + last_tag] * (float)mk[SEQ - 1];
    atomicAdd(out, score - log_den);
  }
}

extern "C" void kernel_launch(void* const* d_in, const int* in_sizes, int n_in,
                              void* d_out, int out_size, void* d_ws, size_t ws_size,
                              hipStream_t stream) {
  const float* logits = (const float*)d_in[0];
  const int*   tags   = (const int*)d_in[1];
  const int*   mask   = (const int*)d_in[2];
  const float* trans  = (const float*)d_in[3];
  float* out = (float*)d_out;

  // workspace: P (16.78 MB bf16 e^logits) + boundary vectors + esums (~16.9 MB)
  unsigned short* P = (unsigned short*)d_ws;
  float* wsA  = (float*)((char*)d_ws + (size_t)BATCH * SEQ * NTAGS * 2);
  float* wsB  = wsA + BATCH * NTAGS;
  int*   wseF = (int*)(wsB + BATCH * NTAGS);
  int*   wseB = wseF + BATCH;

  hipMemsetAsync(out, 0, sizeof(float), stream);  // harness poisons d_out
  crf_prep<<<dim3(BATCH * SEQ * NTAGS / (256 * 8)), dim3(256), 0, stream>>>(logits, (unsigned int*)P);
  crf_halves<<<dim3(4), dim3(NTHREADS), 0, stream>>>(P, mask, trans, wsA, wsB, wseF, wseB);
  crf_combine<<<dim3(BATCH), dim3(256), 0, stream>>>(logits, tags, mask, trans, wsA, wsB, wseF, wseB, out);
}

// Round 8
// 280.104 us; speedup vs baseline: 1.5673x; 1.5673x over previous
//
#include <hip/hip_runtime.h>
#include <stdint.h>

#define NTAGS 256
#define BATCH 64
#define SEQ   512
#define MB    16          // batches per workgroup (the mfma N dimension)
#define NTHREADS 512      // 8 waves; wave w owns tag' rows [32w, 32w+32) -> 2 waves/SIMD

typedef __attribute__((ext_vector_type(8))) short short8;   // 8 bf16 (4 VGPRs)
typedef __attribute__((ext_vector_type(4))) float f32x4;

__device__ __forceinline__ unsigned int f32_to_bf16_bits(float f) {
  unsigned int u = __float_as_uint(f);
  return (u + 0x7FFFu + ((u >> 16) & 1u)) >> 16;
}
__device__ __forceinline__ float wave_sum(float v) {
#pragma unroll
  for (int o = 32; o; o >>= 1) v += __shfl_xor(v, o);
  return v;
}
__device__ __forceinline__ unsigned int pk_bf16(float lo, float hi) {
  unsigned int r;
  asm("v_cvt_pk_bf16_f32 %0, %1, %2" : "=v"(r) : "v"(lo), "v"(hi));
  return r;
}

#define LOG2E 1.4426950408889634f

// lgkm-only barrier: LDS writes ordered; global prefetch loads stay in flight.
// All 8 waves of a block are on the SAME code path (fwd/bwd split is per-BLOCK).
#define BAR_LGKM() \
    asm volatile("s_waitcnt lgkmcnt(0)" ::: "memory"); \
    __builtin_amdgcn_s_barrier(); \
    asm volatile("" ::: "memory");

// One mfma sweep: D[tag',batch] += E' * alpha. 8 K-chunks, 2 M-tiles per wave.
#define MFMA_ALL(RB) \
    f32x4 acc0 = {0.f,0.f,0.f,0.f}, acc1 = {0.f,0.f,0.f,0.f}; \
    _Pragma("unroll") \
    for (int c = 0; c < 8; ++c) { \
      const short8 bf = *(const short8*)&alds[RB][bidxs[c]]; \
      acc0 = __builtin_amdgcn_mfma_f32_16x16x32_bf16(aF[0][c], bf, acc0, 0, 0, 0); \
      acc1 = __builtin_amdgcn_mfma_f32_16x16x32_bf16(aF[1][c], bf, acc1, 0, 0, 0); \
    }

// Forward epilogue tile: C/D layout (m89): lane col=p, rows tag'=32w+16I+4q+r.
// n = (m ? dot*P : old) * 2^-e.  max tracked only when ME (literal 1).
#define EPI_TILE_F(I, ACCI, PB, WB, ME) { \
      const uint2 pw = PB[I]; \
      const float p0_ = __uint_as_float(pw.x << 16); \
      const float p1_ = __uint_as_float(pw.x & 0xFFFF0000u); \
      const float p2_ = __uint_as_float(pw.y << 16); \
      const float p3_ = __uint_as_float(pw.y & 0xFFFF0000u); \
      const float n0 = (MM ? ACCI[0] * p0_ : sOld[I][0]) * sc; \
      const float n1 = (MM ? ACCI[1] * p1_ : sOld[I][1]) * sc; \
      const float n2 = (MM ? ACCI[2] * p2_ : sOld[I][2]) * sc; \
      const float n3 = (MM ? ACCI[3] * p3_ : sOld[I][3]) * sc; \
      sOld[I][0] = n0; sOld[I][1] = n1; sOld[I][2] = n2; sOld[I][3] = n3; \
      if (ME) mxl = fmaxf(mxl, fmaxf(fmaxf(n0, n1), fmaxf(n2, n3))); \
      uint2 wv; wv.x = pk_bf16(n0, n1); wv.y = pk_bf16(n2, n3); \
      *(uint2*)&alds[WB][widx[I]] = wv; }

// Backward epilogue tile: gate m_{t+1}; masked: c_t = c_{t+1} * P_t/P_{t+1} * 2^-e.
#define EPI_TILE_B(I, ACCI, PB, WB, ME) { \
      const uint2 pw = PB[I]; \
      const float p0_ = __uint_as_float(pw.x << 16); \
      const float p1_ = __uint_as_float(pw.x & 0xFFFF0000u); \
      const float p2_ = __uint_as_float(pw.y << 16); \
      const float p3_ = __uint_as_float(pw.y & 0xFFFF0000u); \
      float n0, n1, n2, n3; \
      if (fastm) { \
        n0 = ACCI[0] * p0_ * sc; n1 = ACCI[1] * p1_ * sc; \
        n2 = ACCI[2] * p2_ * sc; n3 = ACCI[3] * p3_ * sc; \
      } else { \
        const float q0_ = __uint_as_float(gp[I].x << 16); \
        const float q1_ = __uint_as_float(gp[I].x & 0xFFFF0000u); \
        const float q2_ = __uint_as_float(gp[I].y << 16); \
        const float q3_ = __uint_as_float(gp[I].y & 0xFFFF0000u); \
        n0 = (MM ? ACCI[0] * p0_ : sOld[I][0] * (p0_ / q0_)) * sc; \
        n1 = (MM ? ACCI[1] * p1_ : sOld[I][1] * (p1_ / q1_)) * sc; \
        n2 = (MM ? ACCI[2] * p2_ : sOld[I][2] * (p2_ / q2_)) * sc; \
        n3 = (MM ? ACCI[3] * p3_ : sOld[I][3] * (p3_ / q3_)) * sc; \
      } \
      gp[I] = pw; \
      sOld[I][0] = n0; sOld[I][1] = n1; sOld[I][2] = n2; sOld[I][3] = n3; \
      if (ME) mxl = fmaxf(mxl, fmaxf(fmaxf(n0, n1), fmaxf(n2, n3))); \
      uint2 wv; wv.x = pk_bf16(n0, n1); wv.y = pk_bf16(n2, n3); \
      *(uint2*)&alds[WB][widx[I]] = wv; }

// Renorm APPLY: max over the 8 per-wave maxes for this batch column.
#define APPLY_BODY() { \
      const f32x4 mxa = *(const f32x4*)&maxw[p][0]; \
      const f32x4 mxb = *(const f32x4*)&maxw[p][4]; \
      const float mx = fmaxf(fmaxf(fmaxf(mxa[0], mxa[1]), fmaxf(mxa[2], mxa[3])), \
                             fmaxf(fmaxf(mxb[0], mxb[1]), fmaxf(mxb[2], mxb[3]))); \
      const int e = (int)((__float_as_uint(mx) >> 23) & 0xFF) - 127; \
      esum += e; \
      sc = __uint_as_float((unsigned int)(127 - e) << 23); }

// One forward step: top-of-step prefetch (4-buffer rotation), one barrier.
#define STEPF(T, RB, WB, PC, PL, MC, ML, APPLY, MEAS) { \
    { const int tp_ = ((T) + 2 < SEQ) ? ((T) + 2) : (SEQ - 1); \
      _Pragma("unroll") \
      for (int i2 = 0; i2 < 2; ++i2) PL[i2] = *(const uint2*)(Pp + (size_t)tp_ * NTAGS + 16 * i2); \
      ML = mkp[tp_]; } \
    MFMA_ALL(RB) \
    float sc = 1.0f; \
    if (APPLY) APPLY_BODY() \
    const int MM = MC; \
    float mxl = -3.0e38f; \
    EPI_TILE_F(0, acc0, PC, WB, MEAS) EPI_TILE_F(1, acc1, PC, WB, MEAS) \
    if (MEAS) { \
      float v = mxl; v = fmaxf(v, __shfl_xor(v, 16)); v = fmaxf(v, __shfl_xor(v, 32)); \
      if (q == 0) maxw[p][wid] = v; \
    } \
    BAR_LGKM() }

#define STEPB(T, RB, WB, PC, PL, MC, ML, APPLY, MEAS) { \
    { const int tp_ = ((T) >= 2) ? ((T) - 2) : 0; \
      const int tm_ = ((T) >= 1) ? ((T) - 1) : 0; \
      _Pragma("unroll") \
      for (int i2 = 0; i2 < 2; ++i2) PL[i2] = *(const uint2*)(Pp + (size_t)tp_ * NTAGS + 16 * i2); \
      ML = mkp[tm_]; } \
    MFMA_ALL(RB) \
    float sc = 1.0f; \
    if (APPLY) APPLY_BODY() \
    const int MM = MC; \
    const bool fastm = (bool)__all(MM != 0); \
    float mxl = -3.0e38f; \
    EPI_TILE_B(0, acc0, PC, WB, MEAS) EPI_TILE_B(1, acc1, PC, WB, MEAS) \
    if (MEAS) { \
      float v = mxl; v = fmaxf(v, __shfl_xor(v, 16)); v = fmaxf(v, __shfl_xor(v, 32)); \
      if (q == 0) maxw[p][wid] = v; \
    } \
    BAR_LGKM() }

// Prep: P[b][t][k] = e^{logits} as bf16. Fully parallel, memory-bound (~10us).
__global__ __launch_bounds__(256)
void crf_prep(const float* __restrict__ lg, unsigned int* __restrict__ P)
{
  const size_t g = (size_t)blockIdx.x * 256 + threadIdx.x;   // 8 floats / thread
  const float4 a = ((const float4*)lg)[2 * g];
  const float4 b = ((const float4*)lg)[2 * g + 1];
  uint4 o;
  o.x = pk_bf16(exp2f(a.x * LOG2E), exp2f(a.y * LOG2E));
  o.y = pk_bf16(exp2f(a.z * LOG2E), exp2f(a.w * LOG2E));
  o.z = pk_bf16(exp2f(b.x * LOG2E), exp2f(b.y * LOG2E));
  o.w = pk_bf16(exp2f(b.z * LOG2E), exp2f(b.w * LOG2E));
  ((uint4*)P)[g] = o;
}

// Pass 1: 8 blocks x 512 threads (8 waves = 2/SIMD; wave w owns 32 tag' rows).
// Blocks 0-3: forward alpha_0 -> alpha_255 (16 batches each).
// Blocks 4-7: backward c_511 -> c_256 -> b_255.
__global__ __launch_bounds__(NTHREADS, 2)
void crf_halves(const unsigned short* __restrict__ P,
                const int*   __restrict__ mask,
                const float* __restrict__ trans,
                float* __restrict__ wsA, float* __restrict__ wsB,
                int* __restrict__ wseF, int* __restrict__ wseB)
{
  const int bid  = blockIdx.x;
  const int bwd  = bid >> 2;
  const int b0   = (bid & 3) * MB;
  const int tid  = threadIdx.x;
  const int wid  = tid >> 6;        // wave 0..7 -> tag' rows [32*wid, +32)
  const int lane = tid & 63;
  const int p    = lane & 15;       // batch column (mfma N / C-col)
  const int q    = lane >> 4;       // k-group (mfma A/B row-group)

  __shared__ __align__(16) short alds[2][NTAGS * MB];  // alpha bf16, dbuf, XOR-swz
  __shared__ __align__(32) float maxw[16][8];          // per-batch per-wave maxes

  const unsigned short* Pp = P + (size_t)(b0 + p) * SEQ * NTAGS + 32 * wid + 4 * q;
  const int* mkp = mask + (b0 + p) * SEQ;

  int bidxs[8], widx[2];
#pragma unroll
  for (int c = 0; c < 8; ++c) bidxs[c] = (p * NTAGS + 32 * c + 8 * q) ^ ((p & 7) << 3);
#pragma unroll
  for (int i = 0; i < 2; ++i) widx[i] = (p * NTAGS + 32 * wid + 16 * i + 4 * q) ^ ((p & 7) << 3);

  // ---- E fragments in registers (constant across steps; 64 VGPRs) ----
  // fwd: A[m=tag',k=tag] = exp(trans[tag, tag']);  bwd: exp(trans[tag', tag]).
  short8 aF[2][8];
#pragma unroll
  for (int i = 0; i < 2; ++i) {
    const int m = 32 * wid + 16 * i + p;   // A-row for this lane
#pragma unroll
    for (int c = 0; c < 8; ++c) {
      short8 w;
#pragma unroll
      for (int j = 0; j < 8; ++j) {
        const int tag = 32 * c + 8 * q + j;
        const float tv = bwd ? trans[m * NTAGS + tag] : trans[tag * NTAGS + m];
        w[j] = (short)f32_to_bf16_bits(exp2f(tv * LOG2E));
      }
      aF[i][c] = w;
    }
  }

  f32x4 sOld[2];
  uint2 p0[2], p1[2], p2[2], p3[2], gp[2];   // P rotation (4 buffers) + bwd prev-P
  int m0 = 1, m1 = 1, m2 = 1, m3 = 1;
  int esum = 0;

  if (!bwd) {
    // ---------------- forward: alpha_0 -> alpha_255 ----------------
#pragma unroll
    for (int i = 0; i < 2; ++i) {
      const uint2 pw = *(const uint2*)(Pp + 16 * i);     // P[t=0]
      f32x4 a;
      a[0] = __uint_as_float(pw.x << 16); a[1] = __uint_as_float(pw.x & 0xFFFF0000u);
      a[2] = __uint_as_float(pw.y << 16); a[3] = __uint_as_float(pw.y & 0xFFFF0000u);
      sOld[i] = a;
      *(uint2*)&alds[0][widx[i]] = pw;                   // already bf16-packed
    }
#pragma unroll
    for (int i = 0; i < 2; ++i) {
      p1[i] = *(const uint2*)(Pp + 1 * NTAGS + 16 * i);
      p2[i] = *(const uint2*)(Pp + 2 * NTAGS + 16 * i);
    }
    m1 = mkp[1]; m2 = mkp[2];
    __syncthreads();

    STEPF(1, 0, 1, p1, p3, m1, m3, 0, 0)
    STEPF(2, 1, 0, p2, p0, m2, m0, 0, 0)
    STEPF(3, 0, 1, p3, p1, m3, m1, 0, 1)
#pragma unroll 1
    for (int tb = 4; tb <= 248; tb += 4) {
      STEPF(tb + 0, 1, 0, p0, p2, m0, m2, 1, 0)
      STEPF(tb + 1, 0, 1, p1, p3, m1, m3, 0, 0)
      STEPF(tb + 2, 1, 0, p2, p0, m2, m0, 0, 0)
      STEPF(tb + 3, 0, 1, p3, p1, m3, m1, 0, 1)
    }
    STEPF(252, 1, 0, p0, p2, m0, m2, 1, 0)
    STEPF(253, 0, 1, p1, p3, m1, m3, 0, 0)
    STEPF(254, 1, 0, p2, p0, m2, m0, 0, 0)

    // final step t=255: no renorm; write f32 alpha_255 to workspace
    {
      MFMA_ALL(0)
      const int MM = m3;    // mk[255] (loaded at T=253)
      float* wp = wsA + (size_t)(b0 + p) * NTAGS + 32 * wid + 4 * q;
#pragma unroll
      for (int i = 0; i < 2; ++i) {
        const uint2 pw = p3[i];   // P[255] (loaded at T=253)
        f32x4 pv;
        pv[0] = __uint_as_float(pw.x << 16); pv[1] = __uint_as_float(pw.x & 0xFFFF0000u);
        pv[2] = __uint_as_float(pw.y << 16); pv[3] = __uint_as_float(pw.y & 0xFFFF0000u);
        f32x4 o;
        const f32x4 ac = (i == 0) ? acc0 : acc1;
#pragma unroll
        for (int r = 0; r < 4; ++r)
          o[r] = MM ? ac[r] * pv[r] : sOld[i][r];
        *(f32x4*)(wp + 16 * i) = o;
      }
    }
    if (tid < 16) wseF[b0 + tid] = esum;
  } else {
    // ---------------- backward: c_511 -> c_256 -> b_255 ----------------
#pragma unroll
    for (int i = 0; i < 2; ++i) {
      const uint2 pw = *(const uint2*)(Pp + (size_t)(SEQ - 1) * NTAGS + 16 * i);  // P[511]
      f32x4 a;
      a[0] = __uint_as_float(pw.x << 16); a[1] = __uint_as_float(pw.x & 0xFFFF0000u);
      a[2] = __uint_as_float(pw.y << 16); a[3] = __uint_as_float(pw.y & 0xFFFF0000u);
      sOld[i] = a; gp[i] = pw;
      *(uint2*)&alds[0][widx[i]] = pw;
    }
#pragma unroll
    for (int i = 0; i < 2; ++i) {
      p2[i] = *(const uint2*)(Pp + (size_t)510 * NTAGS + 16 * i);   // P[510]
      p1[i] = *(const uint2*)(Pp + (size_t)509 * NTAGS + 16 * i);   // P[509]
    }
    m2 = mkp[511];   // gate for T=510 is m_{511}
    m1 = mkp[510];   // gate for T=509 is m_{510}
    __syncthreads();

    STEPB(510, 0, 1, p2, p0, m2, m0, 0, 0)
    STEPB(509, 1, 0, p1, p3, m1, m3, 0, 0)
    STEPB(508, 0, 1, p0, p2, m0, m2, 0, 1)
#pragma unroll 1
    for (int tb = 507; tb >= 263; tb -= 4) {
      STEPB(tb - 0, 1, 0, p3, p1, m3, m1, 1, 0)
      STEPB(tb - 1, 0, 1, p2, p0, m2, m0, 0, 0)
      STEPB(tb - 2, 1, 0, p1, p3, m1, m3, 0, 0)
      STEPB(tb - 3, 0, 1, p0, p2, m0, m2, 0, 1)
    }
    STEPB(259, 1, 0, p3, p1, m3, m1, 1, 0)
    STEPB(258, 0, 1, p2, p0, m2, m0, 0, 0)
    STEPB(257, 1, 0, p1, p3, m1, m3, 0, 0)
    STEPB(256, 0, 1, p0, p2, m0, m2, 0, 0)   // writes c_256 into buf 1

    // bare matvec b_255 = E * c_256 (no e^g), store f32
    {
      MFMA_ALL(1)
      float* wp = wsB + (size_t)(b0 + p) * NTAGS + 32 * wid + 4 * q;
      *(f32x4*)(wp + 0)  = acc0;
      *(f32x4*)(wp + 16) = acc1;
    }
    if (tid < 16) wseB[b0 + tid] = esum;
  }
}

// Pass 2: numerator + den = log(sum a_255 . b_255) + (Ef+Eb)*ln2
__global__ __launch_bounds__(256)
void crf_combine(const float* __restrict__ logits,
                 const int*   __restrict__ tags,
                 const int*   __restrict__ mask,
                 const float* __restrict__ trans,
                 const float* __restrict__ wsA,
                 const float* __restrict__ wsB,
                 const int*   __restrict__ wseF,
                 const int*   __restrict__ wseB,
                 float* __restrict__ out)
{
  const int b    = blockIdx.x;
  const int tid  = threadIdx.x;
  const int lane = tid & 63;
  const int wid  = tid >> 6;   // 0..3

  __shared__ float rn[4], rm[4], rp[4];

  const float LN2 = 0.6931471805599453f;
  const float* lg = logits + (size_t)b * SEQ * NTAGS;
  const int*   tg = tags + b * SEQ;
  const int*   mk = mask + b * SEQ;

  float numer = 0.f, msum = 0.f;
  for (int t = tid; t < SEQ; t += 256) {
    int   tag_t = tg[t];
    float m_t   = (float)mk[t];
    msum += m_t;
    if (t < SEQ - 1) {
      numer += lg[t * NTAGS + tag_t] * m_t;
      numer += trans[tag_t * NTAGS + tg[t + 1]] * (float)mk[t + 1];
    }
  }
  numer = wave_sum(numer);
  msum  = wave_sum(msum);
  if (lane == 0) { rn[wid] = numer; rm[wid] = msum; }

  float pprod = wsA[b * NTAGS + tid] * wsB[b * NTAGS + tid];
  pprod = wave_sum(pprod);
  if (lane == 0) rp[wid] = pprod;
  __syncthreads();

  if (tid == 0) {
    const float numer_tot = (rn[0] + rn[1]) + (rn[2] + rn[3]);
    const float msum_tot  = (rm[0] + rm[1]) + (rm[2] + rm[3]);
    const float psum      = (rp[0] + rp[1]) + (rp[2] + rp[3]);
    const float log_den   = logf(psum) + (float)(wseF[b] + wseB[b]) * LN2;
    int last_idx = (int)msum_tot - 1;
    if (last_idx < 0) last_idx = 0;
    const int last_tag = tg[last_idx];
    const float score = numer_tot + lg[(SEQ - 1) * NTAGS + last_tag] * (float)mk[SEQ - 1];
    atomicAdd(out, score - log_den);
  }
}

extern "C" void kernel_launch(void* const* d_in, const int* in_sizes, int n_in,
                              void* d_out, int out_size, void* d_ws, size_t ws_size,
                              hipStream_t stream) {
  const float* logits = (const float*)d_in[0];
  const int*   tags   = (const int*)d_in[1];
  const int*   mask   = (const int*)d_in[2];
  const float* trans  = (const float*)d_in[3];
  float* out = (float*)d_out;

  // workspace: P (16.78 MB bf16 e^logits) + boundary vectors + esums (~16.9 MB)
  unsigned short* P = (unsigned short*)d_ws;
  float* wsA  = (float*)((char*)d_ws + (size_t)BATCH * SEQ * NTAGS * 2);
  float* wsB  = wsA + BATCH * NTAGS;
  int*   wseF = (int*)(wsB + BATCH * NTAGS);
  int*   wseB = wseF + BATCH;

  hipMemsetAsync(out, 0, sizeof(float), stream);  // harness poisons d_out
  crf_prep<<<dim3(BATCH * SEQ * NTAGS / (256 * 8)), dim3(256), 0, stream>>>(logits, (unsigned int*)P);
  crf_halves<<<dim3(8), dim3(NTHREADS), 0, stream>>>(P, mask, trans, wsA, wsB, wseF, wseB);
  crf_combine<<<dim3(BATCH), dim3(256), 0, stream>>>(logits, tags, mask, trans, wsA, wsB, wseF, wseB, out);
}

// Round 9
// 241.013 us; speedup vs baseline: 1.8215x; 1.1622x over previous
//
#include <hip/hip_runtime.h>
#include <stdint.h>

#define NTAGS 256
#define BATCH 64
#define SEQ   512
#define BR    4           // REAL batches per block; batch cols mirrored x4 across p
#define NTHREADS 512      // 8 waves; wave w owns tag' rows [32w, 32w+32) -> 2 waves/SIMD

typedef __attribute__((ext_vector_type(8))) short short8;   // 8 bf16 (4 VGPRs)
typedef __attribute__((ext_vector_type(4))) float f32x4;

__device__ __forceinline__ unsigned int f32_to_bf16_bits(float f) {
  unsigned int u = __float_as_uint(f);
  return (u + 0x7FFFu + ((u >> 16) & 1u)) >> 16;
}
__device__ __forceinline__ float wave_sum(float v) {
#pragma unroll
  for (int o = 32; o; o >>= 1) v += __shfl_xor(v, o);
  return v;
}
__device__ __forceinline__ unsigned int pk_bf16(float lo, float hi) {
  unsigned int r;
  asm("v_cvt_pk_bf16_f32 %0, %1, %2" : "=v"(r) : "v"(lo), "v"(hi));
  return r;
}

#define LOG2E 1.4426950408889634f

// lgkm-only barrier: LDS writes ordered; global prefetch loads stay in flight.
// All 8 waves of a block are on the SAME code path (fwd/bwd split is per-BLOCK).
#define BAR_LGKM() \
    asm volatile("s_waitcnt lgkmcnt(0)" ::: "memory"); \
    __builtin_amdgcn_s_barrier(); \
    asm volatile("" ::: "memory");

// One mfma sweep: D[tag',batch] += E' * alpha. 8 K-chunks, 2 M-tiles per wave.
// B-frag read from the MIRRORED column (pc = p&3): 4x same-address broadcast
// cuts unique bytes per b128 read to 256B -> ~2 bank phases (swizzle (col&1)<<5).
#define MFMA_ALL(RB) \
    f32x4 acc0 = {0.f,0.f,0.f,0.f}, acc1 = {0.f,0.f,0.f,0.f}; \
    _Pragma("unroll") \
    for (int c = 0; c < 8; ++c) { \
      const short8 bf = *(const short8*)&alds[RB][bidxs[c]]; \
      acc0 = __builtin_amdgcn_mfma_f32_16x16x32_bf16(aF[0][c], bf, acc0, 0, 0, 0); \
      acc1 = __builtin_amdgcn_mfma_f32_16x16x32_bf16(aF[1][c], bf, acc1, 0, 0, 0); \
    }

// Forward epilogue tile: C/D layout (m89): lane col=p, rows tag'=32w+16I+4q+r.
// n = (m ? dot*P : old) * 2^-e.  LDS write guarded to the 4 real columns.
#define EPI_TILE_F(I, ACCI, PB, WB, ME) { \
      const uint2 pw = PB[I]; \
      const float p0_ = __uint_as_float(pw.x << 16); \
      const float p1_ = __uint_as_float(pw.x & 0xFFFF0000u); \
      const float p2_ = __uint_as_float(pw.y << 16); \
      const float p3_ = __uint_as_float(pw.y & 0xFFFF0000u); \
      const float n0 = (MM ? ACCI[0] * p0_ : sOld[I][0]) * sc; \
      const float n1 = (MM ? ACCI[1] * p1_ : sOld[I][1]) * sc; \
      const float n2 = (MM ? ACCI[2] * p2_ : sOld[I][2]) * sc; \
      const float n3 = (MM ? ACCI[3] * p3_ : sOld[I][3]) * sc; \
      sOld[I][0] = n0; sOld[I][1] = n1; sOld[I][2] = n2; sOld[I][3] = n3; \
      if (ME) mxl = fmaxf(mxl, fmaxf(fmaxf(n0, n1), fmaxf(n2, n3))); \
      uint2 wv; wv.x = pk_bf16(n0, n1); wv.y = pk_bf16(n2, n3); \
      if (wrt) *(uint2*)&alds[WB][widx[I]] = wv; }

// Backward epilogue tile: gate m_{t+1}; masked: c_t = c_{t+1} * P_t/P_{t+1} * 2^-e.
#define EPI_TILE_B(I, ACCI, PB, WB, ME) { \
      const uint2 pw = PB[I]; \
      const float p0_ = __uint_as_float(pw.x << 16); \
      const float p1_ = __uint_as_float(pw.x & 0xFFFF0000u); \
      const float p2_ = __uint_as_float(pw.y << 16); \
      const float p3_ = __uint_as_float(pw.y & 0xFFFF0000u); \
      float n0, n1, n2, n3; \
      if (fastm) { \
        n0 = ACCI[0] * p0_ * sc; n1 = ACCI[1] * p1_ * sc; \
        n2 = ACCI[2] * p2_ * sc; n3 = ACCI[3] * p3_ * sc; \
      } else { \
        const float q0_ = __uint_as_float(gp[I].x << 16); \
        const float q1_ = __uint_as_float(gp[I].x & 0xFFFF0000u); \
        const float q2_ = __uint_as_float(gp[I].y << 16); \
        const float q3_ = __uint_as_float(gp[I].y & 0xFFFF0000u); \
        n0 = (MM ? ACCI[0] * p0_ : sOld[I][0] * (p0_ / q0_)) * sc; \
        n1 = (MM ? ACCI[1] * p1_ : sOld[I][1] * (p1_ / q1_)) * sc; \
        n2 = (MM ? ACCI[2] * p2_ : sOld[I][2] * (p2_ / q2_)) * sc; \
        n3 = (MM ? ACCI[3] * p3_ : sOld[I][3] * (p3_ / q3_)) * sc; \
      } \
      gp[I] = pw; \
      sOld[I][0] = n0; sOld[I][1] = n1; sOld[I][2] = n2; sOld[I][3] = n3; \
      if (ME) mxl = fmaxf(mxl, fmaxf(fmaxf(n0, n1), fmaxf(n2, n3))); \
      uint2 wv; wv.x = pk_bf16(n0, n1); wv.y = pk_bf16(n2, n3); \
      if (wrt) *(uint2*)&alds[WB][widx[I]] = wv; }

// Renorm APPLY: max over the 8 per-wave maxes for this (mirrored) batch column.
#define APPLY_BODY() { \
      const f32x4 mxa = *(const f32x4*)&maxw[pc][0]; \
      const f32x4 mxb = *(const f32x4*)&maxw[pc][4]; \
      const float mx = fmaxf(fmaxf(fmaxf(mxa[0], mxa[1]), fmaxf(mxa[2], mxa[3])), \
                             fmaxf(fmaxf(mxb[0], mxb[1]), fmaxf(mxb[2], mxb[3]))); \
      const int e = (int)((__float_as_uint(mx) >> 23) & 0xFF) - 127; \
      esum += e; \
      sc = __uint_as_float((unsigned int)(127 - e) << 23); }

// One forward step: top-of-step prefetch (4-buffer rotation), one barrier.
#define STEPF(T, RB, WB, PC, PL, MC, ML, APPLY, MEAS) { \
    { const int tp_ = ((T) + 2 < SEQ) ? ((T) + 2) : (SEQ - 1); \
      _Pragma("unroll") \
      for (int i2 = 0; i2 < 2; ++i2) PL[i2] = *(const uint2*)(Pp + (size_t)tp_ * NTAGS + 16 * i2); \
      ML = mkp[tp_]; } \
    MFMA_ALL(RB) \
    float sc = 1.0f; \
    if (APPLY) APPLY_BODY() \
    const int MM = MC; \
    float mxl = -3.0e38f; \
    EPI_TILE_F(0, acc0, PC, WB, MEAS) EPI_TILE_F(1, acc1, PC, WB, MEAS) \
    if (MEAS) { \
      float v = mxl; v = fmaxf(v, __shfl_xor(v, 16)); v = fmaxf(v, __shfl_xor(v, 32)); \
      if (q == 0 && wrt) maxw[p][wid] = v; \
    } \
    BAR_LGKM() }

#define STEPB(T, RB, WB, PC, PL, MC, ML, APPLY, MEAS) { \
    { const int tp_ = ((T) >= 2) ? ((T) - 2) : 0; \
      const int tm_ = ((T) >= 1) ? ((T) - 1) : 0; \
      _Pragma("unroll") \
      for (int i2 = 0; i2 < 2; ++i2) PL[i2] = *(const uint2*)(Pp + (size_t)tp_ * NTAGS + 16 * i2); \
      ML = mkp[tm_]; } \
    MFMA_ALL(RB) \
    float sc = 1.0f; \
    if (APPLY) APPLY_BODY() \
    const int MM = MC; \
    const bool fastm = (bool)__all(MM != 0); \
    float mxl = -3.0e38f; \
    EPI_TILE_B(0, acc0, PC, WB, MEAS) EPI_TILE_B(1, acc1, PC, WB, MEAS) \
    if (MEAS) { \
      float v = mxl; v = fmaxf(v, __shfl_xor(v, 16)); v = fmaxf(v, __shfl_xor(v, 32)); \
      if (q == 0 && wrt) maxw[p][wid] = v; \
    } \
    BAR_LGKM() }

// Prep: P[b][t][k] = e^{logits} as bf16. Fully parallel, memory-bound (~10us).
__global__ __launch_bounds__(256)
void crf_prep(const float* __restrict__ lg, unsigned int* __restrict__ P)
{
  const size_t g = (size_t)blockIdx.x * 256 + threadIdx.x;   // 8 floats / thread
  const float4 a = ((const float4*)lg)[2 * g];
  const float4 b = ((const float4*)lg)[2 * g + 1];
  uint4 o;
  o.x = pk_bf16(exp2f(a.x * LOG2E), exp2f(a.y * LOG2E));
  o.y = pk_bf16(exp2f(a.z * LOG2E), exp2f(a.w * LOG2E));
  o.z = pk_bf16(exp2f(b.x * LOG2E), exp2f(b.y * LOG2E));
  o.w = pk_bf16(exp2f(b.z * LOG2E), exp2f(b.w * LOG2E));
  ((uint4*)P)[g] = o;
}

// Pass 1: 32 blocks x 512 threads (8 waves = 2/SIMD; wave w owns 32 tag' rows).
// Blocks 0-15: forward alpha_0 -> alpha_255, 4 real batches each (mirrored x4).
// Blocks 16-31: backward c_511 -> c_256 -> b_255.
__global__ __launch_bounds__(NTHREADS, 2)
void crf_halves(const unsigned short* __restrict__ P,
                const int*   __restrict__ mask,
                const float* __restrict__ trans,
                float* __restrict__ wsA, float* __restrict__ wsB,
                int* __restrict__ wseF, int* __restrict__ wseB)
{
  const int bid  = blockIdx.x;
  const int bwd  = bid >> 4;
  const int b0   = (bid & 15) * BR;
  const int tid  = threadIdx.x;
  const int wid  = tid >> 6;        // wave 0..7 -> tag' rows [32*wid, +32)
  const int lane = tid & 63;
  const int p    = lane & 15;       // mfma N / C-col (16 cols; 4 real, mirrored)
  const int pc   = p & (BR - 1);    // real batch column
  const int q    = lane >> 4;       // k-group (mfma A/B row-group)
  const bool wrt = (p < BR);        // this lane owns a real LDS/global column

  __shared__ __align__(16) short alds[2][NTAGS * BR];  // alpha bf16, dbuf, swizzled
  __shared__ __align__(32) float maxw[BR][8];          // per-batch per-wave maxes

  const unsigned short* Pp = P + (size_t)(b0 + pc) * SEQ * NTAGS + 32 * wid + 4 * q;
  const int* mkp = mask + (b0 + pc) * SEQ;

  // swizzle ^((col&1)<<5) shorts (=64B): read window = q + 4*(col&1) spreads the
  // 16 unique addresses over all 8 bank windows -> 2 full-width phases.
  int bidxs[8], widx[2];
#pragma unroll
  for (int c = 0; c < 8; ++c) bidxs[c] = (pc * NTAGS + 32 * c + 8 * q) ^ ((pc & 1) << 5);
#pragma unroll
  for (int i = 0; i < 2; ++i) widx[i] = (p * NTAGS + 32 * wid + 16 * i + 4 * q) ^ ((p & 1) << 5);

  // ---- E fragments in registers (constant across steps; 64 VGPRs) ----
  // fwd: A[m=tag',k=tag] = exp(trans[tag, tag']);  bwd: exp(trans[tag', tag]).
  short8 aF[2][8];
#pragma unroll
  for (int i = 0; i < 2; ++i) {
    const int m = 32 * wid + 16 * i + p;   // A-row for this lane
#pragma unroll
    for (int c = 0; c < 8; ++c) {
      short8 w;
#pragma unroll
      for (int j = 0; j < 8; ++j) {
        const int tag = 32 * c + 8 * q + j;
        const float tv = bwd ? trans[m * NTAGS + tag] : trans[tag * NTAGS + m];
        w[j] = (short)f32_to_bf16_bits(exp2f(tv * LOG2E));
      }
      aF[i][c] = w;
    }
  }

  f32x4 sOld[2];
  uint2 p0[2], p1[2], p2[2], p3[2], gp[2];   // P rotation (4 buffers) + bwd prev-P
  int m0 = 1, m1 = 1, m2 = 1, m3 = 1;
  int esum = 0;

  if (!bwd) {
    // ---------------- forward: alpha_0 -> alpha_255 ----------------
#pragma unroll
    for (int i = 0; i < 2; ++i) {
      const uint2 pw = *(const uint2*)(Pp + 16 * i);     // P[t=0]
      f32x4 a;
      a[0] = __uint_as_float(pw.x << 16); a[1] = __uint_as_float(pw.x & 0xFFFF0000u);
      a[2] = __uint_as_float(pw.y << 16); a[3] = __uint_as_float(pw.y & 0xFFFF0000u);
      sOld[i] = a;
      if (wrt) *(uint2*)&alds[0][widx[i]] = pw;          // already bf16-packed
    }
#pragma unroll
    for (int i = 0; i < 2; ++i) {
      p1[i] = *(const uint2*)(Pp + 1 * NTAGS + 16 * i);
      p2[i] = *(const uint2*)(Pp + 2 * NTAGS + 16 * i);
    }
    m1 = mkp[1]; m2 = mkp[2];
    __syncthreads();

    STEPF(1, 0, 1, p1, p3, m1, m3, 0, 0)
    STEPF(2, 1, 0, p2, p0, m2, m0, 0, 0)
    STEPF(3, 0, 1, p3, p1, m3, m1, 0, 1)
#pragma unroll 1
    for (int tb = 4; tb <= 248; tb += 4) {
      STEPF(tb + 0, 1, 0, p0, p2, m0, m2, 1, 0)
      STEPF(tb + 1, 0, 1, p1, p3, m1, m3, 0, 0)
      STEPF(tb + 2, 1, 0, p2, p0, m2, m0, 0, 0)
      STEPF(tb + 3, 0, 1, p3, p1, m3, m1, 0, 1)
    }
    STEPF(252, 1, 0, p0, p2, m0, m2, 1, 0)
    STEPF(253, 0, 1, p1, p3, m1, m3, 0, 0)
    STEPF(254, 1, 0, p2, p0, m2, m0, 0, 0)

    // final step t=255: no renorm; write f32 alpha_255 to workspace
    {
      MFMA_ALL(0)
      const int MM = m3;    // mk[255] (loaded at T=253)
      float* wp = wsA + (size_t)(b0 + pc) * NTAGS + 32 * wid + 4 * q;
#pragma unroll
      for (int i = 0; i < 2; ++i) {
        const uint2 pw = p3[i];   // P[255] (loaded at T=253)
        f32x4 pv;
        pv[0] = __uint_as_float(pw.x << 16); pv[1] = __uint_as_float(pw.x & 0xFFFF0000u);
        pv[2] = __uint_as_float(pw.y << 16); pv[3] = __uint_as_float(pw.y & 0xFFFF0000u);
        f32x4 o;
        const f32x4 ac = (i == 0) ? acc0 : acc1;
#pragma unroll
        for (int r = 0; r < 4; ++r)
          o[r] = MM ? ac[r] * pv[r] : sOld[i][r];
        if (wrt) *(f32x4*)(wp + 16 * i) = o;
      }
    }
    if (tid < BR) wseF[b0 + tid] = esum;
  } else {
    // ---------------- backward: c_511 -> c_256 -> b_255 ----------------
#pragma unroll
    for (int i = 0; i < 2; ++i) {
      const uint2 pw = *(const uint2*)(Pp + (size_t)(SEQ - 1) * NTAGS + 16 * i);  // P[511]
      f32x4 a;
      a[0] = __uint_as_float(pw.x << 16); a[1] = __uint_as_float(pw.x & 0xFFFF0000u);
      a[2] = __uint_as_float(pw.y << 16); a[3] = __uint_as_float(pw.y & 0xFFFF0000u);
      sOld[i] = a; gp[i] = pw;
      if (wrt) *(uint2*)&alds[0][widx[i]] = pw;
    }
#pragma unroll
    for (int i = 0; i < 2; ++i) {
      p2[i] = *(const uint2*)(Pp + (size_t)510 * NTAGS + 16 * i);   // P[510]
      p1[i] = *(const uint2*)(Pp + (size_t)509 * NTAGS + 16 * i);   // P[509]
    }
    m2 = mkp[511];   // gate for T=510 is m_{511}
    m1 = mkp[510];   // gate for T=509 is m_{510}
    __syncthreads();

    STEPB(510, 0, 1, p2, p0, m2, m0, 0, 0)
    STEPB(509, 1, 0, p1, p3, m1, m3, 0, 0)
    STEPB(508, 0, 1, p0, p2, m0, m2, 0, 1)
#pragma unroll 1
    for (int tb = 507; tb >= 263; tb -= 4) {
      STEPB(tb - 0, 1, 0, p3, p1, m3, m1, 1, 0)
      STEPB(tb - 1, 0, 1, p2, p0, m2, m0, 0, 0)
      STEPB(tb - 2, 1, 0, p1, p3, m1, m3, 0, 0)
      STEPB(tb - 3, 0, 1, p0, p2, m0, m2, 0, 1)
    }
    STEPB(259, 1, 0, p3, p1, m3, m1, 1, 0)
    STEPB(258, 0, 1, p2, p0, m2, m0, 0, 0)
    STEPB(257, 1, 0, p1, p3, m1, m3, 0, 0)
    STEPB(256, 0, 1, p0, p2, m0, m2, 0, 0)   // writes c_256 into buf 1

    // bare matvec b_255 = E * c_256 (no e^g), store f32
    {
      MFMA_ALL(1)
      float* wp = wsB + (size_t)(b0 + pc) * NTAGS + 32 * wid + 4 * q;
      if (wrt) {
        *(f32x4*)(wp + 0)  = acc0;
        *(f32x4*)(wp + 16) = acc1;
      }
    }
    if (tid < BR) wseB[b0 + tid] = esum;
  }
}

// Pass 2: numerator + den = log(sum a_255 . b_255) + (Ef+Eb)*ln2
__global__ __launch_bounds__(256)
void crf_combine(const float* __restrict__ logits,
                 const int*   __restrict__ tags,
                 const int*   __restrict__ mask,
                 const float* __restrict__ trans,
                 const float* __restrict__ wsA,
                 const float* __restrict__ wsB,
                 const int*   __restrict__ wseF,
                 const int*   __restrict__ wseB,
                 float* __restrict__ out)
{
  const int b    = blockIdx.x;
  const int tid  = threadIdx.x;
  const int lane = tid & 63;
  const int wid  = tid >> 6;   // 0..3

  __shared__ float rn[4], rm[4], rp[4];

  const float LN2 = 0.6931471805599453f;
  const float* lg = logits + (size_t)b * SEQ * NTAGS;
  const int*   tg = tags + b * SEQ;
  const int*   mk = mask + b * SEQ;

  float numer = 0.f, msum = 0.f;
  for (int t = tid; t < SEQ; t += 256) {
    int   tag_t = tg[t];
    float m_t   = (float)mk[t];
    msum += m_t;
    if (t < SEQ - 1) {
      numer += lg[t * NTAGS + tag_t] * m_t;
      numer += trans[tag_t * NTAGS + tg[t + 1]] * (float)mk[t + 1];
    }
  }
  numer = wave_sum(numer);
  msum  = wave_sum(msum);
  if (lane == 0) { rn[wid] = numer; rm[wid] = msum; }

  float pprod = wsA[b * NTAGS + tid] * wsB[b * NTAGS + tid];
  pprod = wave_sum(pprod);
  if (lane == 0) rp[wid] = pprod;
  __syncthreads();

  if (tid == 0) {
    const float numer_tot = (rn[0] + rn[1]) + (rn[2] + rn[3]);
    const float msum_tot  = (rm[0] + rm[1]) + (rm[2] + rm[3]);
    const float psum      = (rp[0] + rp[1]) + (rp[2] + rp[3]);
    const float log_den   = logf(psum) + (float)(wseF[b] + wseB[b]) * LN2;
    int last_idx = (int)msum_tot - 1;
    if (last_idx < 0) last_idx = 0;
    const int last_tag = tg[last_idx];
    const float score = numer_tot + lg[(SEQ - 1) * NTAGS + last_tag] * (float)mk[SEQ - 1];
    atomicAdd(out, score - log_den);
  }
}

extern "C" void kernel_launch(void* const* d_in, const int* in_sizes, int n_in,
                              void* d_out, int out_size, void* d_ws, size_t ws_size,
                              hipStream_t stream) {
  const float* logits = (const float*)d_in[0];
  const int*   tags   = (const int*)d_in[1];
  const int*   mask   = (const int*)d_in[2];
  const float* trans  = (const float*)d_in[3];
  float* out = (float*)d_out;

  // workspace: P (16.78 MB bf16 e^logits) + boundary vectors + esums (~16.9 MB)
  unsigned short* P = (unsigned short*)d_ws;
  float* wsA  = (float*)((char*)d_ws + (size_t)BATCH * SEQ * NTAGS * 2);
  float* wsB  = wsA + BATCH * NTAGS;
  int*   wseF = (int*)(wsB + BATCH * NTAGS);
  int*   wseB = wseF + BATCH;

  hipMemsetAsync(out, 0, sizeof(float), stream);  // harness poisons d_out
  crf_prep<<<dim3(BATCH * SEQ * NTAGS / (256 * 8)), dim3(256), 0, stream>>>(logits, (unsigned int*)P);
  crf_halves<<<dim3(32), dim3(NTHREADS), 0, stream>>>(P, mask, trans, wsA, wsB, wseF, wseB);
  crf_combine<<<dim3(BATCH), dim3(256), 0, stream>>>(logits, tags, mask, trans, wsA, wsB, wseF, wseB, out);
}

// Round 10
// 237.802 us; speedup vs baseline: 1.8461x; 1.0135x over previous
//
#include <hip/hip_runtime.h>
#include <stdint.h>

#define NTAGS 256
#define BATCH 64
#define SEQ   512
#define NTHREADS 512      // 8 waves; wave w owns tag' rows [32w, 32w+32) -> 2 waves/SIMD

typedef __attribute__((ext_vector_type(8))) short short8;   // 8 bf16 (4 VGPRs)
typedef __attribute__((ext_vector_type(4))) float f32x4;

__device__ __forceinline__ unsigned int f32_to_bf16_bits(float f) {
  unsigned int u = __float_as_uint(f);
  return (u + 0x7FFFu + ((u >> 16) & 1u)) >> 16;
}
__device__ __forceinline__ float wave_sum(float v) {
#pragma unroll
  for (int o = 32; o; o >>= 1) v += __shfl_xor(v, o);
  return v;
}
__device__ __forceinline__ unsigned int pk_bf16(float lo, float hi) {
  unsigned int r;
  asm("v_cvt_pk_bf16_f32 %0, %1, %2" : "=v"(r) : "v"(lo), "v"(hi));
  return r;
}

#define LOG2E 1.4426950408889634f

// lgkm-only barrier: LDS writes ordered; global prefetch loads stay in flight.
#define BAR_LGKM() \
    asm volatile("s_waitcnt lgkmcnt(0)" ::: "memory"); \
    __builtin_amdgcn_s_barrier(); \
    asm volatile("" ::: "memory");

// One mfma sweep: D[tag',batch] += E' * alpha. 8 K-chunks, 2 M-tiles per wave.
// BR=1: alpha row is 512B; read at chunk c touches banks 16c+4q+{0..3} only --
// 16 distinct banks, 16-lane same-address broadcast each. Conflict-free.
#define MFMA_ALL(RB) \
    f32x4 acc0 = {0.f,0.f,0.f,0.f}, acc1 = {0.f,0.f,0.f,0.f}; \
    _Pragma("unroll") \
    for (int c = 0; c < 8; ++c) { \
      const short8 bf = *(const short8*)&alds[RB][bidxs[c]]; \
      acc0 = __builtin_amdgcn_mfma_f32_16x16x32_bf16(aF[0][c], bf, acc0, 0, 0, 0); \
      acc1 = __builtin_amdgcn_mfma_f32_16x16x32_bf16(aF[1][c], bf, acc1, 0, 0, 0); \
    }

// Forward epilogue tile: C/D layout (m89): lane col=p (mirrored), rows tag'=32w+16I+4q+r.
// AP literal folds the *sc multiply away on non-APPLY steps.
#define EPI_TILE_F(I, ACCI, PB, WB, ME, AP) { \
      const uint2 pw = PB[I]; \
      const float p0_ = __uint_as_float(pw.x << 16); \
      const float p1_ = __uint_as_float(pw.x & 0xFFFF0000u); \
      const float p2_ = __uint_as_float(pw.y << 16); \
      const float p3_ = __uint_as_float(pw.y & 0xFFFF0000u); \
      float n0, n1, n2, n3; \
      if (fastm) { \
        n0 = ACCI[0] * p0_; n1 = ACCI[1] * p1_; \
        n2 = ACCI[2] * p2_; n3 = ACCI[3] * p3_; \
      } else { \
        n0 = MM ? ACCI[0] * p0_ : sOld[I][0]; \
        n1 = MM ? ACCI[1] * p1_ : sOld[I][1]; \
        n2 = MM ? ACCI[2] * p2_ : sOld[I][2]; \
        n3 = MM ? ACCI[3] * p3_ : sOld[I][3]; \
      } \
      if (AP) { n0 *= sc; n1 *= sc; n2 *= sc; n3 *= sc; } \
      sOld[I][0] = n0; sOld[I][1] = n1; sOld[I][2] = n2; sOld[I][3] = n3; \
      if (ME) mxl = fmaxf(mxl, fmaxf(fmaxf(n0, n1), fmaxf(n2, n3))); \
      uint2 wv; wv.x = pk_bf16(n0, n1); wv.y = pk_bf16(n2, n3); \
      if (wrt) *(uint2*)&alds[WB][widx[I]] = wv; }

// Backward epilogue tile: gate m_{t+1}; masked: c_t = c_{t+1} * P_t/P_{t+1}.
#define EPI_TILE_B(I, ACCI, PB, WB, ME, AP) { \
      const uint2 pw = PB[I]; \
      const float p0_ = __uint_as_float(pw.x << 16); \
      const float p1_ = __uint_as_float(pw.x & 0xFFFF0000u); \
      const float p2_ = __uint_as_float(pw.y << 16); \
      const float p3_ = __uint_as_float(pw.y & 0xFFFF0000u); \
      float n0, n1, n2, n3; \
      if (fastm) { \
        n0 = ACCI[0] * p0_; n1 = ACCI[1] * p1_; \
        n2 = ACCI[2] * p2_; n3 = ACCI[3] * p3_; \
      } else { \
        const float q0_ = __uint_as_float(gp[I].x << 16); \
        const float q1_ = __uint_as_float(gp[I].x & 0xFFFF0000u); \
        const float q2_ = __uint_as_float(gp[I].y << 16); \
        const float q3_ = __uint_as_float(gp[I].y & 0xFFFF0000u); \
        n0 = MM ? ACCI[0] * p0_ : sOld[I][0] * (p0_ / q0_); \
        n1 = MM ? ACCI[1] * p1_ : sOld[I][1] * (p1_ / q1_); \
        n2 = MM ? ACCI[2] * p2_ : sOld[I][2] * (p2_ / q2_); \
        n3 = MM ? ACCI[3] * p3_ : sOld[I][3] * (p3_ / q3_); \
      } \
      if (AP) { n0 *= sc; n1 *= sc; n2 *= sc; n3 *= sc; } \
      gp[I] = pw; \
      sOld[I][0] = n0; sOld[I][1] = n1; sOld[I][2] = n2; sOld[I][3] = n3; \
      if (ME) mxl = fmaxf(mxl, fmaxf(fmaxf(n0, n1), fmaxf(n2, n3))); \
      uint2 wv; wv.x = pk_bf16(n0, n1); wv.y = pk_bf16(n2, n3); \
      if (wrt) *(uint2*)&alds[WB][widx[I]] = wv; }

// Renorm APPLY: max over the 8 per-wave maxes (single batch per block).
#define APPLY_BODY() { \
      const f32x4 mxa = *(const f32x4*)&maxw[0]; \
      const f32x4 mxb = *(const f32x4*)&maxw[4]; \
      const float mx = fmaxf(fmaxf(fmaxf(mxa[0], mxa[1]), fmaxf(mxa[2], mxa[3])), \
                             fmaxf(fmaxf(mxb[0], mxb[1]), fmaxf(mxb[2], mxb[3]))); \
      const int e = (int)((__float_as_uint(mx) >> 23) & 0xFF) - 127; \
      esum += e; \
      sc = __uint_as_float((unsigned int)(127 - e) << 23); }

// One forward step: top-of-step prefetch (4-buffer rotation), one barrier.
#define STEPF(T, RB, WB, PC, PL, MC, ML, APPLY, MEAS) { \
    { const int tp_ = ((T) + 2 < SEQ) ? ((T) + 2) : (SEQ - 1); \
      _Pragma("unroll") \
      for (int i2 = 0; i2 < 2; ++i2) PL[i2] = *(const uint2*)(Pp + (size_t)tp_ * NTAGS + 16 * i2); \
      ML = mkp[tp_]; } \
    MFMA_ALL(RB) \
    float sc = 1.0f; \
    if (APPLY) APPLY_BODY() \
    const int MM = MC; \
    const bool fastm = (bool)__all(MM != 0); \
    float mxl = -3.0e38f; \
    EPI_TILE_F(0, acc0, PC, WB, MEAS, APPLY) EPI_TILE_F(1, acc1, PC, WB, MEAS, APPLY) \
    if (MEAS) { \
      float v = mxl; v = fmaxf(v, __shfl_xor(v, 16)); v = fmaxf(v, __shfl_xor(v, 32)); \
      if (q == 0 && wrt) maxw[wid] = v; \
    } \
    BAR_LGKM() }

#define STEPB(T, RB, WB, PC, PL, MC, ML, APPLY, MEAS) { \
    { const int tp_ = ((T) >= 2) ? ((T) - 2) : 0; \
      const int tm_ = ((T) >= 1) ? ((T) - 1) : 0; \
      _Pragma("unroll") \
      for (int i2 = 0; i2 < 2; ++i2) PL[i2] = *(const uint2*)(Pp + (size_t)tp_ * NTAGS + 16 * i2); \
      ML = mkp[tm_]; } \
    MFMA_ALL(RB) \
    float sc = 1.0f; \
    if (APPLY) APPLY_BODY() \
    const int MM = MC; \
    const bool fastm = (bool)__all(MM != 0); \
    float mxl = -3.0e38f; \
    EPI_TILE_B(0, acc0, PC, WB, MEAS, APPLY) EPI_TILE_B(1, acc1, PC, WB, MEAS, APPLY) \
    if (MEAS) { \
      float v = mxl; v = fmaxf(v, __shfl_xor(v, 16)); v = fmaxf(v, __shfl_xor(v, 32)); \
      if (q == 0 && wrt) maxw[wid] = v; \
    } \
    BAR_LGKM() }

// Prep: P[b][t][k] = e^{logits} as bf16. Fully parallel, memory-bound (~10us).
__global__ __launch_bounds__(256)
void crf_prep(const float* __restrict__ lg, unsigned int* __restrict__ P)
{
  const size_t g = (size_t)blockIdx.x * 256 + threadIdx.x;   // 8 floats / thread
  const float4 a = ((const float4*)lg)[2 * g];
  const float4 b = ((const float4*)lg)[2 * g + 1];
  uint4 o;
  o.x = pk_bf16(exp2f(a.x * LOG2E), exp2f(a.y * LOG2E));
  o.y = pk_bf16(exp2f(a.z * LOG2E), exp2f(a.w * LOG2E));
  o.z = pk_bf16(exp2f(b.x * LOG2E), exp2f(b.y * LOG2E));
  o.w = pk_bf16(exp2f(b.z * LOG2E), exp2f(b.w * LOG2E));
  ((uint4*)P)[g] = o;
}

// Pass 1: 128 blocks x 512 threads (8 waves = 2/SIMD; wave w owns 32 tag' rows).
// Blocks 0-63: forward alpha_0 -> alpha_255 for batch bid (mfma cols mirrored x16).
// Blocks 64-127: backward c_511 -> c_256 -> b_255.
__global__ __launch_bounds__(NTHREADS, 2)
void crf_halves(const unsigned short* __restrict__ P,
                const int*   __restrict__ mask,
                const float* __restrict__ trans,
                float* __restrict__ wsA, float* __restrict__ wsB,
                int* __restrict__ wseF, int* __restrict__ wseB)
{
  const int bid  = blockIdx.x;
  const int bwd  = bid >> 6;
  const int b    = bid & 63;        // the single real batch for this block
  const int tid  = threadIdx.x;
  const int wid  = tid >> 6;        // wave 0..7 -> tag' rows [32*wid, +32)
  const int lane = tid & 63;
  const int p    = lane & 15;       // mfma N / C-col (all 16 mirror batch b)
  const int q    = lane >> 4;       // k-group (mfma A/B row-group)
  const bool wrt = (p == 0);        // lane owns the real column

  __shared__ __align__(16) short alds[2][NTAGS];   // alpha bf16, dbuf (512B each)
  __shared__ __align__(32) float maxw[8];          // per-wave renorm maxes

  const unsigned short* Pp = P + (size_t)b * SEQ * NTAGS + 32 * wid + 4 * q;
  const int* mkp = mask + b * SEQ;

  int bidxs[8], widx[2];
#pragma unroll
  for (int c = 0; c < 8; ++c) bidxs[c] = 32 * c + 8 * q;
#pragma unroll
  for (int i = 0; i < 2; ++i) widx[i] = 32 * wid + 16 * i + 4 * q;

  // ---- E fragments in registers (constant across steps; 64 VGPRs) ----
  // fwd: A[m=tag',k=tag] = exp(trans[tag, tag']);  bwd: exp(trans[tag', tag]).
  short8 aF[2][8];
#pragma unroll
  for (int i = 0; i < 2; ++i) {
    const int m = 32 * wid + 16 * i + p;   // A-row for this lane
#pragma unroll
    for (int c = 0; c < 8; ++c) {
      short8 w;
#pragma unroll
      for (int j = 0; j < 8; ++j) {
        const int tag = 32 * c + 8 * q + j;
        const float tv = bwd ? trans[m * NTAGS + tag] : trans[tag * NTAGS + m];
        w[j] = (short)f32_to_bf16_bits(exp2f(tv * LOG2E));
      }
      aF[i][c] = w;
    }
  }

  f32x4 sOld[2];
  uint2 p0[2], p1[2], p2[2], p3[2], gp[2];   // P rotation (4 buffers) + bwd prev-P
  int m0 = 1, m1 = 1, m2 = 1, m3 = 1;
  int esum = 0;

  if (!bwd) {
    // ---------------- forward: alpha_0 -> alpha_255 ----------------
#pragma unroll
    for (int i = 0; i < 2; ++i) {
      const uint2 pw = *(const uint2*)(Pp + 16 * i);     // P[t=0]
      f32x4 a;
      a[0] = __uint_as_float(pw.x << 16); a[1] = __uint_as_float(pw.x & 0xFFFF0000u);
      a[2] = __uint_as_float(pw.y << 16); a[3] = __uint_as_float(pw.y & 0xFFFF0000u);
      sOld[i] = a;
      if (wrt) *(uint2*)&alds[0][widx[i]] = pw;          // already bf16-packed
    }
#pragma unroll
    for (int i = 0; i < 2; ++i) {
      p1[i] = *(const uint2*)(Pp + 1 * NTAGS + 16 * i);
      p2[i] = *(const uint2*)(Pp + 2 * NTAGS + 16 * i);
    }
    m1 = mkp[1]; m2 = mkp[2];
    __syncthreads();

    STEPF(1, 0, 1, p1, p3, m1, m3, 0, 0)
    STEPF(2, 1, 0, p2, p0, m2, m0, 0, 0)
    STEPF(3, 0, 1, p3, p1, m3, m1, 0, 1)
#pragma unroll 1
    for (int tb = 4; tb <= 248; tb += 4) {
      STEPF(tb + 0, 1, 0, p0, p2, m0, m2, 1, 0)
      STEPF(tb + 1, 0, 1, p1, p3, m1, m3, 0, 0)
      STEPF(tb + 2, 1, 0, p2, p0, m2, m0, 0, 0)
      STEPF(tb + 3, 0, 1, p3, p1, m3, m1, 0, 1)
    }
    STEPF(252, 1, 0, p0, p2, m0, m2, 1, 0)
    STEPF(253, 0, 1, p1, p3, m1, m3, 0, 0)
    STEPF(254, 1, 0, p2, p0, m2, m0, 0, 0)

    // final step t=255: no renorm; write f32 alpha_255 to workspace
    {
      MFMA_ALL(0)
      const int MM = m3;    // mk[255] (loaded at T=253)
      float* wp = wsA + (size_t)b * NTAGS + 32 * wid + 4 * q;
#pragma unroll
      for (int i = 0; i < 2; ++i) {
        const uint2 pw = p3[i];   // P[255] (loaded at T=253)
        f32x4 pv;
        pv[0] = __uint_as_float(pw.x << 16); pv[1] = __uint_as_float(pw.x & 0xFFFF0000u);
        pv[2] = __uint_as_float(pw.y << 16); pv[3] = __uint_as_float(pw.y & 0xFFFF0000u);
        f32x4 o;
        const f32x4 ac = (i == 0) ? acc0 : acc1;
#pragma unroll
        for (int r = 0; r < 4; ++r)
          o[r] = MM ? ac[r] * pv[r] : sOld[i][r];
        if (wrt) *(f32x4*)(wp + 16 * i) = o;
      }
    }
    if (tid == 0) wseF[b] = esum;
  } else {
    // ---------------- backward: c_511 -> c_256 -> b_255 ----------------
#pragma unroll
    for (int i = 0; i < 2; ++i) {
      const uint2 pw = *(const uint2*)(Pp + (size_t)(SEQ - 1) * NTAGS + 16 * i);  // P[511]
      f32x4 a;
      a[0] = __uint_as_float(pw.x << 16); a[1] = __uint_as_float(pw.x & 0xFFFF0000u);
      a[2] = __uint_as_float(pw.y << 16); a[3] = __uint_as_float(pw.y & 0xFFFF0000u);
      sOld[i] = a; gp[i] = pw;
      if (wrt) *(uint2*)&alds[0][widx[i]] = pw;
    }
#pragma unroll
    for (int i = 0; i < 2; ++i) {
      p2[i] = *(const uint2*)(Pp + (size_t)510 * NTAGS + 16 * i);   // P[510]
      p1[i] = *(const uint2*)(Pp + (size_t)509 * NTAGS + 16 * i);   // P[509]
    }
    m2 = mkp[511];   // gate for T=510 is m_{511}
    m1 = mkp[510];   // gate for T=509 is m_{510}
    __syncthreads();

    STEPB(510, 0, 1, p2, p0, m2, m0, 0, 0)
    STEPB(509, 1, 0, p1, p3, m1, m3, 0, 0)
    STEPB(508, 0, 1, p0, p2, m0, m2, 0, 1)
#pragma unroll 1
    for (int tb = 507; tb >= 263; tb -= 4) {
      STEPB(tb - 0, 1, 0, p3, p1, m3, m1, 1, 0)
      STEPB(tb - 1, 0, 1, p2, p0, m2, m0, 0, 0)
      STEPB(tb - 2, 1, 0, p1, p3, m1, m3, 0, 0)
      STEPB(tb - 3, 0, 1, p0, p2, m0, m2, 0, 1)
    }
    STEPB(259, 1, 0, p3, p1, m3, m1, 1, 0)
    STEPB(258, 0, 1, p2, p0, m2, m0, 0, 0)
    STEPB(257, 1, 0, p1, p3, m1, m3, 0, 0)
    STEPB(256, 0, 1, p0, p2, m0, m2, 0, 0)   // writes c_256 into buf 1

    // bare matvec b_255 = E * c_256 (no e^g), store f32
    {
      MFMA_ALL(1)
      float* wp = wsB + (size_t)b * NTAGS + 32 * wid + 4 * q;
      if (wrt) {
        *(f32x4*)(wp + 0)  = acc0;
        *(f32x4*)(wp + 16) = acc1;
      }
    }
    if (tid == 0) wseB[b] = esum;
  }
}

// Pass 2: numerator + den = log(sum a_255 . b_255) + (Ef+Eb)*ln2
__global__ __launch_bounds__(256)
void crf_combine(const float* __restrict__ logits,
                 const int*   __restrict__ tags,
                 const int*   __restrict__ mask,
                 const float* __restrict__ trans,
                 const float* __restrict__ wsA,
                 const float* __restrict__ wsB,
                 const int*   __restrict__ wseF,
                 const int*   __restrict__ wseB,
                 float* __restrict__ out)
{
  const int b    = blockIdx.x;
  const int tid  = threadIdx.x;
  const int lane = tid & 63;
  const int wid  = tid >> 6;   // 0..3

  __shared__ float rn[4], rm[4], rp[4];

  const float LN2 = 0.6931471805599453f;
  const float* lg = logits + (size_t)b * SEQ * NTAGS;
  const int*   tg = tags + b * SEQ;
  const int*   mk = mask + b * SEQ;

  float numer = 0.f, msum = 0.f;
  for (int t = tid; t < SEQ; t += 256) {
    int   tag_t = tg[t];
    float m_t   = (float)mk[t];
    msum += m_t;
    if (t < SEQ - 1) {
      numer += lg[t * NTAGS + tag_t] * m_t;
      numer += trans[tag_t * NTAGS + tg[t + 1]] * (float)mk[t + 1];
    }
  }
  numer = wave_sum(numer);
  msum  = wave_sum(msum);
  if (lane == 0) { rn[wid] = numer; rm[wid] = msum; }

  float pprod = wsA[b * NTAGS + tid] * wsB[b * NTAGS + tid];
  pprod = wave_sum(pprod);
  if (lane == 0) rp[wid] = pprod;
  __syncthreads();

  if (tid == 0) {
    const float numer_tot = (rn[0] + rn[1]) + (rn[2] + rn[3]);
    const float msum_tot  = (rm[0] + rm[1]) + (rm[2] + rm[3]);
    const float psum      = (rp[0] + rp[1]) + (rp[2] + rp[3]);
    const float log_den   = logf(psum) + (float)(wseF[b] + wseB[b]) * LN2;
    int last_idx = (int)msum_tot - 1;
    if (last_idx < 0) last_idx = 0;
    const int last_tag = tg[last_idx];
    const float score = numer_tot + lg[(SEQ - 1) * NTAGS + last_tag] * (float)mk[SEQ - 1];
    atomicAdd(out, score - log_den);
  }
}

extern "C" void kernel_launch(void* const* d_in, const int* in_sizes, int n_in,
                              void* d_out, int out_size, void* d_ws, size_t ws_size,
                              hipStream_t stream) {
  const float* logits = (const float*)d_in[0];
  const int*   tags   = (const int*)d_in[1];
  const int*   mask   = (const int*)d_in[2];
  const float* trans  = (const float*)d_in[3];
  float* out = (float*)d_out;

  // workspace: P (16.78 MB bf16 e^logits) + boundary vectors + esums (~16.9 MB)
  unsigned short* P = (unsigned short*)d_ws;
  float* wsA  = (float*)((char*)d_ws + (size_t)BATCH * SEQ * NTAGS * 2);
  float* wsB  = wsA + BATCH * NTAGS;
  int*   wseF = (int*)(wsB + BATCH * NTAGS);
  int*   wseB = wseF + BATCH;

  hipMemsetAsync(out, 0, sizeof(float), stream);  // harness poisons d_out
  crf_prep<<<dim3(BATCH * SEQ * NTAGS / (256 * 8)), dim3(256), 0, stream>>>(logits, (unsigned int*)P);
  crf_halves<<<dim3(128), dim3(NTHREADS), 0, stream>>>(P, mask, trans, wsA, wsB, wseF, wseB);
  crf_combine<<<dim3(BATCH), dim3(256), 0, stream>>>(logits, tags, mask, trans, wsA, wsB, wseF, wseB, out);
}